// Round 2
// baseline (19169.821 us; speedup 1.0000x reference)
//
#include <hip/hip_runtime.h>
#include <cstddef>

#define Bn 32
#define Sn 512
#define Hn 512
#define Rn (Bn*Sn)
#define NLAYER 4
constexpr size_t NHe = (size_t)Rn * Hn;   // 8,388,608 elements per (B,S,H) tensor

__device__ __forceinline__ float sigf(float x) { return 1.f / (1.f + __expf(-x)); }
__device__ __forceinline__ float4 f4z() { return make_float4(0.f, 0.f, 0.f, 0.f); }
__device__ __forceinline__ float4 f4add(float4 a, float4 b) {
  return make_float4(a.x + b.x, a.y + b.y, a.z + b.z, a.w + b.w);
}

// ---------------- init: h = init_h*m, c = init_c*m ----------------
__global__ void k_init(const float* __restrict__ ih, const float* __restrict__ ic,
                       const int* __restrict__ mask,
                       float* __restrict__ h, float* __restrict__ c) {
  size_t i = (size_t)blockIdx.x * blockDim.x + threadIdx.x;  // over NHe/4
  size_t n = i >> 7;
  float m = (float)mask[n];
  float4 b = ((const float4*)ih)[i];
  float4 d = ((const float4*)ic)[i];
  b.x *= m; b.y *= m; b.z *= m; b.w *= m;
  d.x *= m; d.y *= m; d.z *= m; d.w *= m;
  ((float4*)h)[i] = b; ((float4*)c)[i] = d;
}

// ---------------- mean over s ----------------
__global__ void k_mean1(const float* __restrict__ x, float* __restrict__ ox) {
  int idx = blockIdx.x * blockDim.x + threadIdx.x;  // B*H
  int b = idx >> 9, k = idx & 511;
  const float* px = x + (size_t)b * Sn * Hn + k;
  float s = 0.f;
#pragma unroll 8
  for (int t = 0; t < Sn; ++t) s += px[(size_t)t * Hn];
  ox[idx] = s * (1.f / Sn);
}
__global__ void k_mean2(const float* __restrict__ x, const float* __restrict__ y,
                        float* __restrict__ ox, float* __restrict__ oy) {
  int idx = blockIdx.x * blockDim.x + threadIdx.x;
  int b = idx >> 9, k = idx & 511;
  const float* px = x + (size_t)b * Sn * Hn + k;
  const float* py = y + (size_t)b * Sn * Hn + k;
  float sx = 0.f, sy = 0.f;
#pragma unroll 8
  for (int t = 0; t < Sn; ++t) { sx += px[(size_t)t * Hn]; sy += py[(size_t)t * Hn]; }
  ox[idx] = sx * (1.f / Sn); oy[idx] = sy * (1.f / Sn);
}

// ---------------- small gates: gd, go, gfA (= dummy_h@gWxf + gbf) ----------------
__global__ void k_gates_small(const float* __restrict__ dh, const float* __restrict__ comb,
                              const float* __restrict__ gW, const float* __restrict__ gb,
                              float* __restrict__ gd, float* __restrict__ go,
                              float* __restrict__ gfA) {
  int idx = blockIdx.x * blockDim.x + threadIdx.x;  // B*H
  int b = idx >> 9, k = idx & 511;
  const float* gW0 = gW;                       // gWxd
  const float* gW1 = gW + 1 * Hn * Hn;         // gWhd
  const float* gW2 = gW + 2 * Hn * Hn;         // gWxo
  const float* gW3 = gW + 3 * Hn * Hn;         // gWho
  const float* gW4 = gW + 4 * Hn * Hn;         // gWxf
  const float* dhb = dh + b * Hn;
  const float* cbp = comb + b * Hn;
  float s0 = 0.f, s1 = 0.f, s2 = 0.f, s3 = 0.f, s4 = 0.f;
#pragma unroll 4
  for (int j = 0; j < Hn; ++j) {
    float a = dhb[j], c2 = cbp[j];
    s0 += a * gW0[j * Hn + k];
    s1 += c2 * gW1[j * Hn + k];
    s2 += a * gW2[j * Hn + k];
    s3 += c2 * gW3[j * Hn + k];
    s4 += a * gW4[j * Hn + k];
  }
  gd[idx] = sigf(s0 + s1 + gb[k]);
  go[idx] = sigf(s2 + s3 + gb[Hn + k]);
  gfA[idx] = s4 + gb[2 * Hn + k];
}

// ---------------- dWd[g,b,k] = dummy_h[b,:] @ Wd[g,:,k] ----------------
__global__ void k_dWd(const float* __restrict__ dh, const float* __restrict__ Wd,
                      float* __restrict__ dWd) {
  int idx = blockIdx.x * blockDim.x + threadIdx.x;  // 8*B*H
  int k = idx & 511; int bg = idx >> 9; int b = bg & 31; int g = bg >> 5;
  const float* w = Wd + (size_t)g * Hn * Hn;
  const float* dhb = dh + b * Hn;
  float s = 0.f;
#pragma unroll 4
  for (int j = 0; j < Hn; ++j) s += dhb[j] * w[j * Hn + k];
  dWd[idx] = s;
}

// ---------------- single SGEMM: G = h @ gWhf (M=Rn, N=K=Hn) ----------------
__global__ __launch_bounds__(256, 2) void k_gemm1(const float* __restrict__ A,
                                                  const float* __restrict__ B,
                                                  float* __restrict__ C) {
  __shared__ float As[16][132];
  __shared__ float Bs[16][132];
  const int m0 = blockIdx.x * 128;
  const int n0 = blockIdx.y * 128;
  const int tid = threadIdx.x;
  const int tx = tid & 15, ty = tid >> 4;
  float acc[8][8];
#pragma unroll
  for (int i = 0; i < 8; ++i)
#pragma unroll
    for (int j = 0; j < 8; ++j) acc[i][j] = 0.f;

  const float* At = A + (size_t)m0 * Hn;
  const float* Bt = B + n0;
  for (int kc = 0; kc < Hn; kc += 16) {
    __syncthreads();
#pragma unroll
    for (int u = 0; u < 2; ++u) {
      int id = u * 256 + tid;
      int ar = id >> 2, ac = (id & 3) << 2;
      float4 av = *(const float4*)(At + (size_t)ar * Hn + kc + ac);
      As[ac + 0][ar] = av.x; As[ac + 1][ar] = av.y;
      As[ac + 2][ar] = av.z; As[ac + 3][ar] = av.w;
      int br = id >> 5, bc = (id & 31) << 2;
      float4 bv = *(const float4*)(Bt + (size_t)(kc + br) * Hn + bc);
      *(float4*)&Bs[br][bc] = bv;
    }
    __syncthreads();
#pragma unroll
    for (int kk = 0; kk < 16; ++kk) {
      float a_[8], b_[8];
#pragma unroll
      for (int i = 0; i < 8; ++i) a_[i] = As[kk][ty * 8 + i];
#pragma unroll
      for (int j = 0; j < 8; ++j) b_[j] = Bs[kk][tx * 8 + j];
#pragma unroll
      for (int i = 0; i < 8; ++i)
#pragma unroll
        for (int j = 0; j < 8; ++j) acc[i][j] = fmaf(a_[i], b_[j], acc[i][j]);
    }
  }
#pragma unroll
  for (int i = 0; i < 8; ++i) {
    int row = m0 + ty * 8 + i;
#pragma unroll
    for (int j = 0; j < 8; ++j) C[(size_t)row * Hn + n0 + tx * 8 + j] = acc[i][j];
  }
}

// ---------------- dummy gate update: softmax over (S+1) streamed ----------------
__global__ void k_dummy(const float* __restrict__ G, const float* __restrict__ gfA,
                        const float* __restrict__ gd, const float* __restrict__ go,
                        const float* __restrict__ c, const float* __restrict__ dc,
                        const int* __restrict__ mask,
                        float* __restrict__ dh2, float* __restrict__ dc2) {
  int idx = blockIdx.x * blockDim.x + threadIdx.x;  // B*H
  int b = idx >> 9, k = idx & 511;
  float gfa = gfA[idx];
  float ed = __expf(gd[idx]);             // gd already sigmoid'ed
  float num = ed * dc[idx], den = ed;
  const float* Gp = G + (size_t)b * Sn * Hn + k;
  const float* cp = c + (size_t)b * Sn * Hn + k;
  const int* mp = mask + b * Sn;
#pragma unroll 4
  for (int s = 0; s < Sn; ++s) {
    float e = __expf(sigf(Gp[(size_t)s * Hn] + gfa));
    e = mp[s] ? e : 0.f;                  // mask_score = -1e25 -> exp = 0
    num += e * cp[(size_t)s * Hn];
    den += e;
  }
  float d = num / den;
  dc2[idx] = d;
  dh2[idx] = go[idx] * tanhf(d);
}

// ---------------- mega GEMM: all 8 groups, 5 terms, fused gate epilogue ----------------
#define BM 64
#define BN 64
#define BK 16

__global__ __launch_bounds__(256, 2) void k_mega(
    const float* __restrict__ h, const float* __restrict__ c,
    const float* __restrict__ word, const int* __restrict__ pos,
    const int* __restrict__ mask, const float* __restrict__ dc,
    const float* __restrict__ dWd, const float* __restrict__ bias,
    const float* __restrict__ Wx, const float* __restrict__ Wh,
    const float* __restrict__ Ws, const float* __restrict__ Wi,
    float* __restrict__ hout, float* __restrict__ cout) {
  __shared__ float As[BK][BM + 4];
  __shared__ float Bs[8][BK][BN + 4];

  const int tid = threadIdx.x;
  const int tx = tid & 15, ty = tid >> 4;
  const int m0 = blockIdx.x * BM;
  const int n0 = blockIdx.y * BN;
  const int bb = m0 >> 9;     // batch index (BM=64 divides S=512: tile is single-batch)

  float acc[8][16];
#pragma unroll
  for (int g = 0; g < 8; ++g)
#pragma unroll
    for (int e = 0; e < 16; ++e) acc[g][e] = 0.f;

  const float4* h4 = (const float4*)h;
  const float4* w4 = (const float4*)word;

  // per-thread A staging coordinates (fixed across kc)
  const int ar = tid >> 2;                // row within tile [0,64)
  const int ac = (tid & 3) << 2;          // col-offset within BK {0,4,8,12}
  const int grow = m0 + ar;               // global row
  const int srow = grow & (Sn - 1);
  const int pA = pos[grow];
  const float mrowf = (float)mask[grow];
  const size_t f0 = (size_t)grow * 128;   // float4 row base
  const size_t fsw = pA ? ((size_t)(bb * Sn + pA - 1)) * 128 : 0;

#pragma unroll 1
  for (int t = 0; t < 5; ++t) {
    const float* Bbase; long gs;
    if (t == 0)      { Bbase = Wx;                       gs = (long)Hn * Hn; }
    else if (t == 1) { Bbase = Wh;                       gs = (long)2 * Hn * Hn; }
    else if (t == 2) { Bbase = Wh + (size_t)Hn * Hn;     gs = (long)2 * Hn * Hn; }
    else if (t == 3) { Bbase = Ws;                       gs = (long)Hn * Hn; }
    else             { Bbase = Wi;                       gs = (long)Hn * Hn; }

#pragma unroll 1
    for (int kc = 0; kc < Hn; kc += BK) {
      __syncthreads();
      // ---- stage A (64x16), term-dependent source ----
      const int c4i = (kc + ac) >> 2;
      float4 av;
      if (t == 0) {
        av = h4[f0 + c4i];
      } else if (t == 1) {
        float4 x1 = (srow >= 1) ? h4[f0 - 128 + c4i] : f4z();
        float4 x2 = (srow >= 2) ? h4[f0 - 256 + c4i] : f4z();
        av = f4add(x1, x2);
      } else if (t == 2) {
        float4 x1 = (srow <= Sn - 2) ? h4[f0 + 128 + c4i] : f4z();
        float4 x2 = (srow <= Sn - 3) ? h4[f0 + 256 + c4i] : f4z();
        av = f4add(x1, x2);
      } else if (t == 3) {
        av = pA ? h4[fsw + c4i] : f4z();
      } else {
        av = w4[f0 + c4i];
        av.x *= mrowf; av.y *= mrowf; av.z *= mrowf; av.w *= mrowf;
      }
      As[ac + 0][ar] = av.x; As[ac + 1][ar] = av.y;
      As[ac + 2][ar] = av.z; As[ac + 3][ar] = av.w;
      // ---- stage B: 8 groups x (16x64) ----
#pragma unroll
      for (int u = 0; u < 8; ++u) {
        int id = u * 256 + tid;
        int g = id >> 8;
        int rid = id & 255;
        int br = rid >> 4, bc = (rid & 15) << 2;
        const float* bp = Bbase + (size_t)g * gs + (size_t)(kc + br) * Hn + n0 + bc;
        float4 bv = *(const float4*)bp;
        *(float4*)&Bs[g][br][bc] = bv;
      }
      __syncthreads();
      // ---- accumulate ----
#pragma unroll 4
      for (int kk = 0; kk < BK; ++kk) {
        float4 a = *(const float4*)&As[kk][ty * 4];
        float aa[4] = {a.x, a.y, a.z, a.w};
#pragma unroll
        for (int g = 0; g < 8; ++g) {
          float4 bv = *(const float4*)&Bs[g][kk][tx * 4];
          float bw[4] = {bv.x, bv.y, bv.z, bv.w};
#pragma unroll
          for (int i = 0; i < 4; ++i)
#pragma unroll
            for (int j = 0; j < 4; ++j)
              acc[g][i * 4 + j] = fmaf(aa[i], bw[j], acc[g][i * 4 + j]);
        }
      }
    }
  }

  // ---- fused epilogue: gates + cell/hidden update ----
  const float4* c4p = (const float4*)c;
  const int colq = (n0 >> 2) + tx;        // float4 column index
  float4 bias4[8], dwd4[8];
#pragma unroll
  for (int g = 0; g < 8; ++g) {
    bias4[g] = ((const float4*)bias)[g * 128 + colq];
    dwd4[g]  = ((const float4*)dWd)[((size_t)g * Bn + bb) * 128 + colq];
  }
  const float4 tdc = ((const float4*)dc)[bb * 128 + colq];

#pragma unroll
  for (int i = 0; i < 4; ++i) {
    const int row = m0 + ty * 4 + i;
    const int s = row & (Sn - 1);
    const float mf = (float)mask[row];
    const size_t rb = (size_t)row * 128;
    float4 cf = c4p[rb + colq];
    float4 cb = f4z(), ca = f4z();
    if (s >= 1) cb = c4p[rb - 128 + colq];
    if (s >= 2) cb = f4add(cb, c4p[rb - 256 + colq]);
    if (s <= Sn - 2) ca = c4p[rb + 128 + colq];
    if (s <= Sn - 3) ca = f4add(ca, c4p[rb + 256 + colq]);
    const int pp = pos[row];
    float4 sw = pp ? c4p[((size_t)(bb * Sn + pp - 1)) * 128 + colq] : f4z();

    float4 oc, oh;
    float* ocp = (float*)&oc; float* ohp = (float*)&oh;
#pragma unroll
    for (int j = 0; j < 4; ++j) {
      float z[8];
#pragma unroll
      for (int g = 0; g < 8; ++g)
        z[g] = acc[g][i * 4 + j] + ((const float*)&bias4[g])[j] + ((const float*)&dwd4[g])[j];
      float e0 = __expf(sigf(z[0]));
      float e1 = __expf(sigf(z[1]));
      float e2 = __expf(sigf(z[2]));
      float e3 = __expf(sigf(z[3]));
      float e4 = __expf(sigf(z[4]));
      float e5 = __expf(sigf(z[5]));
      float inv = 1.f / (e0 + e1 + e2 + e3 + e4 + e5);
      float o = sigf(z[6]);
      float u = tanhf(z[7]);
      float cn = inv * (e0 * ((const float*)&cb)[j] + e1 * ((const float*)&ca)[j]
                      + e2 * ((const float*)&cf)[j] + e3 * ((const float*)&tdc)[j]
                      + e4 * ((const float*)&sw)[j] + e5 * u);
      ocp[j] = cn * mf;
      ohp[j] = o * tanhf(cn) * mf;
    }
    ((float4*)cout)[rb + colq] = oc;
    ((float4*)hout)[rb + colq] = oh;
  }
}

extern "C" void kernel_launch(void* const* d_in, const int* in_sizes, int n_in,
                              void* d_out, int out_size, void* d_ws, size_t ws_size,
                              hipStream_t stream) {
  (void)in_sizes; (void)n_in; (void)out_size; (void)ws_size;
  const float* word   = (const float*)d_in[0];
  const float* init_h = (const float*)d_in[1];
  const float* init_c = (const float*)d_in[2];
  const float* Wx     = (const float*)d_in[3];
  const float* Wh     = (const float*)d_in[4];
  const float* Wi     = (const float*)d_in[5];
  const float* Wdm    = (const float*)d_in[6];
  const float* Wsm    = (const float*)d_in[7];
  const float* bias   = (const float*)d_in[8];
  const float* gW     = (const float*)d_in[9];
  const float* gb     = (const float*)d_in[10];
  const int*   pos    = (const int*)d_in[11];
  const int*   mask   = (const int*)d_in[12];

  float* ws = (float*)d_ws;
  size_t off = 0;
  auto alloc = [&](size_t nel) { float* p = ws + off; off += nel; return p; };
  float* hA   = alloc(NHe);
  float* hB   = alloc(NHe);
  float* cA   = alloc(NHe);
  float* cB   = alloc(NHe);
  float* G    = alloc(NHe);
  float* dh   = alloc(Bn * Hn);
  float* dc   = alloc(Bn * Hn);
  float* dh2  = alloc(Bn * Hn);
  float* dc2  = alloc(Bn * Hn);
  float* comb = alloc(Bn * Hn);
  float* gd   = alloc(Bn * Hn);
  float* go   = alloc(Bn * Hn);
  float* gfA  = alloc(Bn * Hn);
  float* dWd  = alloc(8 * Bn * Hn);
  // total: 5*NHe + 262144 floats = 168.8 MB

  dim3 blk(256);
  int g4 = (int)(NHe / 4 / 256);          // 8192 blocks
  int gbh = (Bn * Hn) / 256;              // 64 blocks

  k_init<<<g4, blk, 0, stream>>>(init_h, init_c, mask, hA, cA);
  k_mean2<<<gbh, blk, 0, stream>>>(hA, cA, dh, dc);

  float* hcur = hA; float* hnxt = hB; float* ccur = cA; float* cnxt = cB;
  for (int l = 0; l < NLAYER; ++l) {
    k_mean1<<<gbh, blk, 0, stream>>>(hcur, comb);
    k_gates_small<<<gbh, blk, 0, stream>>>(dh, comb, gW, gb, gd, go, gfA);
    k_dWd<<<(8 * Bn * Hn) / 256, blk, 0, stream>>>(dh, Wdm, dWd);
    k_gemm1<<<dim3(Rn / 128, Hn / 128), blk, 0, stream>>>(hcur, gW + (size_t)5 * Hn * Hn, G);
    k_dummy<<<gbh, blk, 0, stream>>>(G, gfA, gd, go, ccur, dc, mask, dh2, dc2);

    float* hout = (l == NLAYER - 1) ? (float*)d_out : hnxt;
    k_mega<<<dim3(Rn / BM, Hn / BN), blk, 0, stream>>>(
        hcur, ccur, word, pos, mask, dc, dWd, bias, Wx, Wh, Wsm, Wi, hout, cnxt);

    float* t1;
    t1 = hcur; hcur = hnxt; hnxt = t1;
    t1 = ccur; ccur = cnxt; cnxt = t1;
    t1 = dh; dh = dh2; dh2 = t1;
    t1 = dc; dc = dc2; dc2 = t1;
  }
}

// Round 3
// 4594.946 us; speedup vs baseline: 4.1719x; 4.1719x over previous
//
#include <hip/hip_runtime.h>
#include <cstddef>

#define Bn 32
#define Sn 512
#define Hn 512
#define Rn (Bn*Sn)
#define NLAYER 4
constexpr size_t NHe = (size_t)Rn * Hn;   // 8,388,608 elements per (B,S,H) tensor

typedef __attribute__((ext_vector_type(8))) short bf16x8;
typedef __attribute__((ext_vector_type(4))) float f32x4;

__device__ __forceinline__ float sigf(float x) { return 1.f / (1.f + __expf(-x)); }
__device__ __forceinline__ float4 f4z() { return make_float4(0.f, 0.f, 0.f, 0.f); }
__device__ __forceinline__ float4 f4add(float4 a, float4 b) {
  return make_float4(a.x + b.x, a.y + b.y, a.z + b.z, a.w + b.w);
}
// round-to-nearest-even f32 -> bf16 (as raw uint16)
__device__ __forceinline__ unsigned short bfh(float x) {
  unsigned u = __float_as_uint(x);
  u += 0x7fffu + ((u >> 16) & 1u);
  return (unsigned short)(u >> 16);
}

// ---------------- init: h = init_h*m, c = init_c*m ----------------
__global__ void k_init(const float* __restrict__ ih, const float* __restrict__ ic,
                       const int* __restrict__ mask,
                       float* __restrict__ h, float* __restrict__ c) {
  size_t i = (size_t)blockIdx.x * blockDim.x + threadIdx.x;  // over NHe/4
  size_t n = i >> 7;
  float m = (float)mask[n];
  float4 b = ((const float4*)ih)[i];
  float4 d = ((const float4*)ic)[i];
  b.x *= m; b.y *= m; b.z *= m; b.w *= m;
  d.x *= m; d.y *= m; d.z *= m; d.w *= m;
  ((float4*)h)[i] = b; ((float4*)c)[i] = d;
}

// ---------------- mean over s ----------------
__global__ void k_mean1(const float* __restrict__ x, float* __restrict__ ox) {
  int idx = blockIdx.x * blockDim.x + threadIdx.x;  // B*H
  int b = idx >> 9, k = idx & 511;
  const float* px = x + (size_t)b * Sn * Hn + k;
  float s = 0.f;
#pragma unroll 8
  for (int t = 0; t < Sn; ++t) s += px[(size_t)t * Hn];
  ox[idx] = s * (1.f / Sn);
}
__global__ void k_mean2(const float* __restrict__ x, const float* __restrict__ y,
                        float* __restrict__ ox, float* __restrict__ oy) {
  int idx = blockIdx.x * blockDim.x + threadIdx.x;
  int b = idx >> 9, k = idx & 511;
  const float* px = x + (size_t)b * Sn * Hn + k;
  const float* py = y + (size_t)b * Sn * Hn + k;
  float sx = 0.f, sy = 0.f;
#pragma unroll 8
  for (int t = 0; t < Sn; ++t) { sx += px[(size_t)t * Hn]; sy += py[(size_t)t * Hn]; }
  ox[idx] = sx * (1.f / Sn); oy[idx] = sy * (1.f / Sn);
}

// ---------------- small gates: gd, go, gfA (= dummy_h@gWxf + gbf) ----------------
__global__ void k_gates_small(const float* __restrict__ dh, const float* __restrict__ comb,
                              const float* __restrict__ gW, const float* __restrict__ gb,
                              float* __restrict__ gd, float* __restrict__ go,
                              float* __restrict__ gfA) {
  int idx = blockIdx.x * blockDim.x + threadIdx.x;  // B*H
  int b = idx >> 9, k = idx & 511;
  const float* gW0 = gW;
  const float* gW1 = gW + 1 * Hn * Hn;
  const float* gW2 = gW + 2 * Hn * Hn;
  const float* gW3 = gW + 3 * Hn * Hn;
  const float* gW4 = gW + 4 * Hn * Hn;
  const float* dhb = dh + b * Hn;
  const float* cbp = comb + b * Hn;
  float s0 = 0.f, s1 = 0.f, s2 = 0.f, s3 = 0.f, s4 = 0.f;
#pragma unroll 4
  for (int j = 0; j < Hn; ++j) {
    float a = dhb[j], c2 = cbp[j];
    s0 += a * gW0[j * Hn + k];
    s1 += c2 * gW1[j * Hn + k];
    s2 += a * gW2[j * Hn + k];
    s3 += c2 * gW3[j * Hn + k];
    s4 += a * gW4[j * Hn + k];
  }
  gd[idx] = sigf(s0 + s1 + gb[k]);
  go[idx] = sigf(s2 + s3 + gb[Hn + k]);
  gfA[idx] = s4 + gb[2 * Hn + k];
}

// ---------------- dWd[g,b,k] = dummy_h[b,:] @ Wd[g,:,k] ----------------
__global__ void k_dWd(const float* __restrict__ dh, const float* __restrict__ Wd,
                      float* __restrict__ dWd) {
  int idx = blockIdx.x * blockDim.x + threadIdx.x;  // 8*B*H
  int k = idx & 511; int bg = idx >> 9; int b = bg & 31; int g = bg >> 5;
  const float* w = Wd + (size_t)g * Hn * Hn;
  const float* dhb = dh + b * Hn;
  float s = 0.f;
#pragma unroll 4
  for (int j = 0; j < Hn; ++j) s += dhb[j] * w[j * Hn + k];
  dWd[idx] = s;
}

// ---------------- single SGEMM: G = h @ gWhf (M=Rn, N=K=Hn) ----------------
__global__ __launch_bounds__(256, 2) void k_gemm1(const float* __restrict__ A,
                                                  const float* __restrict__ B,
                                                  float* __restrict__ C) {
  __shared__ float As[16][132];
  __shared__ float Bs[16][132];
  const int m0 = blockIdx.x * 128;
  const int n0 = blockIdx.y * 128;
  const int tid = threadIdx.x;
  const int tx = tid & 15, ty = tid >> 4;
  float acc[8][8];
#pragma unroll
  for (int i = 0; i < 8; ++i)
#pragma unroll
    for (int j = 0; j < 8; ++j) acc[i][j] = 0.f;

  const float* At = A + (size_t)m0 * Hn;
  const float* Bt = B + n0;
  for (int kc = 0; kc < Hn; kc += 16) {
    __syncthreads();
#pragma unroll
    for (int u = 0; u < 2; ++u) {
      int id = u * 256 + tid;
      int ar = id >> 2, ac = (id & 3) << 2;
      float4 av = *(const float4*)(At + (size_t)ar * Hn + kc + ac);
      As[ac + 0][ar] = av.x; As[ac + 1][ar] = av.y;
      As[ac + 2][ar] = av.z; As[ac + 3][ar] = av.w;
      int br = id >> 5, bc = (id & 31) << 2;
      float4 bv = *(const float4*)(Bt + (size_t)(kc + br) * Hn + bc);
      *(float4*)&Bs[br][bc] = bv;
    }
    __syncthreads();
#pragma unroll
    for (int kk = 0; kk < 16; ++kk) {
      float a_[8], b_[8];
#pragma unroll
      for (int i = 0; i < 8; ++i) a_[i] = As[kk][ty * 8 + i];
#pragma unroll
      for (int j = 0; j < 8; ++j) b_[j] = Bs[kk][tx * 8 + j];
#pragma unroll
      for (int i = 0; i < 8; ++i)
#pragma unroll
        for (int j = 0; j < 8; ++j) acc[i][j] = fmaf(a_[i], b_[j], acc[i][j]);
    }
  }
#pragma unroll
  for (int i = 0; i < 8; ++i) {
    int row = m0 + ty * 8 + i;
#pragma unroll
    for (int j = 0; j < 8; ++j) C[(size_t)row * Hn + n0 + tx * 8 + j] = acc[i][j];
  }
}

// ---------------- dummy gate update: softmax over (S+1) streamed ----------------
__global__ void k_dummy(const float* __restrict__ G, const float* __restrict__ gfA,
                        const float* __restrict__ gd, const float* __restrict__ go,
                        const float* __restrict__ c, const float* __restrict__ dc,
                        const int* __restrict__ mask,
                        float* __restrict__ dh2, float* __restrict__ dc2) {
  int idx = blockIdx.x * blockDim.x + threadIdx.x;  // B*H
  int b = idx >> 9, k = idx & 511;
  float gfa = gfA[idx];
  float ed = __expf(gd[idx]);
  float num = ed * dc[idx], den = ed;
  const float* Gp = G + (size_t)b * Sn * Hn + k;
  const float* cp = c + (size_t)b * Sn * Hn + k;
  const int* mp = mask + b * Sn;
#pragma unroll 4
  for (int s = 0; s < Sn; ++s) {
    float e = __expf(sigf(Gp[(size_t)s * Hn] + gfa));
    e = mp[s] ? e : 0.f;
    num += e * cp[(size_t)s * Hn];
    den += e;
  }
  float d = num / den;
  dc2[idx] = d;
  dh2[idx] = go[idx] * tanhf(d);
}

// ---------------- weight pre-swizzle: f32 [g][k][n] -> bf16 frag-order superblocks ----------------
// Bhat layout: superblock sb = (t*16 + nT)*16 + kcT, 8192 shorts (16KB) each.
// Interior: (((g*2 + ni)*4 + quad)*16 + l15)*8 + j
//   element: term t, group g, n = nT*32 + ni*16 + l15, k = kcT*32 + quad*8 + j
__global__ void k_convw(const float* __restrict__ Wx, const float* __restrict__ Wh,
                        const float* __restrict__ Wsm, const float* __restrict__ Wi,
                        short* __restrict__ Bhat) {
  int kcT = blockIdx.x, nT = blockIdx.y, tg = blockIdx.z;  // 16,16,40
  int t = tg >> 3, g = tg & 7;
  const float* base;
  if (t == 0)      base = Wx  + (size_t)g * 262144;
  else if (t == 1) base = Wh  + (size_t)g * 524288;
  else if (t == 2) base = Wh  + (size_t)g * 524288 + 262144;
  else if (t == 3) base = Wsm + (size_t)g * 262144;
  else             base = Wi  + (size_t)g * 262144;
  size_t sbase = ((size_t)(t * 16 + nT) * 16 + kcT) * 8192 + (size_t)g * 1024;
  int lane = threadIdx.x;  // 64 threads
  for (int cch = lane; cch < 128; cch += 64) {
    int ni = cch >> 6, quad = (cch >> 4) & 3, l15 = cch & 15;
    int n = nT * 32 + ni * 16 + l15;
    int k0 = kcT * 32 + quad * 8;
#pragma unroll
    for (int j = 0; j < 8; ++j)
      Bhat[sbase + (size_t)cch * 8 + j] = (short)bfh(base[(size_t)(k0 + j) * Hn + n]);
  }
}

// ---------------- mega GEMM (MFMA split-bf16): all 8 groups, 5 terms, fused gate epilogue ----------------
// BM=128, BN=32, BK=32, 256 threads = 4 waves; wave w owns rows [w*32, w*32+32), all 32 cols.
__global__ __launch_bounds__(256, 2) void k_mega(
    const float* __restrict__ h, const float* __restrict__ c,
    const float* __restrict__ word, const short* __restrict__ Bhat,
    const int* __restrict__ pos, const int* __restrict__ mask,
    const float* __restrict__ dc, const float* __restrict__ dWd,
    const float* __restrict__ bias,
    float* __restrict__ hout, float* __restrict__ cout) {
  // frag-ordered LDS: A: [rg(8)][quad(4)][l15(16)][8] ; B: [g(8)][ni(2)][quad(4)][l15(16)][8]
  __shared__ bf16x8 AsH8[512];
  __shared__ bf16x8 AsL8[512];
  __shared__ bf16x8 Bs8[1024];
  short* AsH = (short*)AsH8;
  short* AsL = (short*)AsL8;
  short* Bs  = (short*)Bs8;

  const int tid = threadIdx.x;
  const int id = blockIdx.x;        // 2048
  const int xcd = id & 7;
  const int loc = id >> 3;          // 0..255
  const int nT = xcd * 2 + (loc >> 7);
  const int mb = loc & 127;
  const int m0 = mb * 128;
  const int n0 = nT * 32;
  const int bb = m0 >> 9;           // batch index (tile spans one batch)

  // ---- fixed A-staging coords: thread covers (row = m0 + tid/2, k in [koff0, koff0+16)) ----
  const int arow = m0 + (tid >> 1);
  const int srowA = arow & (Sn - 1);
  const int koff0 = (tid & 1) * 16;
  const int pA = pos[arow];
  const float mA = (float)mask[arow];
  const size_t f0 = (size_t)arow * 128;       // float4 row base
  const size_t fsw = pA ? ((size_t)(bb * Sn + pA - 1)) * 128 : 0;
  const int rgA = (tid >> 1) >> 4;
  const int l15A = (tid >> 1) & 15;
  const int qA = (tid & 1) * 2;               // first quad this thread fills
  const int wb0 = ((rgA * 4 + qA) * 16 + l15A) * 8;
  const int wb1 = ((rgA * 4 + qA + 1) * 16 + l15A) * 8;

  const int lane = tid & 63, wid = tid >> 6;
  const int quad = lane >> 4, l15 = lane & 15;

  f32x4 acc[8][2][2];
#pragma unroll
  for (int g = 0; g < 8; ++g)
#pragma unroll
    for (int mi = 0; mi < 2; ++mi)
#pragma unroll
      for (int ni = 0; ni < 2; ++ni) acc[g][mi][ni] = (f32x4){0.f, 0.f, 0.f, 0.f};

  const float4* h4 = (const float4*)h;
  const float4* w4 = (const float4*)word;

  // A-fragment LDS read offsets (elements)
  const int afo0 = (((wid * 2 + 0) * 4 + quad) * 16 + l15) * 8;
  const int afo1 = (((wid * 2 + 1) * 4 + quad) * 16 + l15) * 8;

#pragma unroll 1
  for (int t = 0; t < 5; ++t) {
#pragma unroll 1
    for (int kc = 0; kc < Hn; kc += 32) {
      __syncthreads();
      // ---- stage A: 16 f32 -> hi/lo bf16 ----
      const int c4 = (kc + koff0) >> 2;
      float vv[16];
#pragma unroll
      for (int q = 0; q < 4; ++q) {
        float4 v;
        if (t == 0) v = h4[f0 + c4 + q];
        else if (t == 1) {
          v = (srowA >= 1) ? h4[f0 - 128 + c4 + q] : f4z();
          if (srowA >= 2) v = f4add(v, h4[f0 - 256 + c4 + q]);
        } else if (t == 2) {
          v = (srowA <= Sn - 2) ? h4[f0 + 128 + c4 + q] : f4z();
          if (srowA <= Sn - 3) v = f4add(v, h4[f0 + 256 + c4 + q]);
        } else if (t == 3) {
          v = pA ? h4[fsw + c4 + q] : f4z();
        } else {
          v = w4[f0 + c4 + q];
          v.x *= mA; v.y *= mA; v.z *= mA; v.w *= mA;
        }
        vv[q * 4 + 0] = v.x; vv[q * 4 + 1] = v.y; vv[q * 4 + 2] = v.z; vv[q * 4 + 3] = v.w;
      }
      bf16x8 h0, h1, l0, l1;
#pragma unroll
      for (int j = 0; j < 8; ++j) {
        unsigned short hh = bfh(vv[j]);
        h0[j] = (short)hh;
        l0[j] = (short)bfh(vv[j] - __uint_as_float((unsigned)hh << 16));
        unsigned short hh1 = bfh(vv[8 + j]);
        h1[j] = (short)hh1;
        l1[j] = (short)bfh(vv[8 + j] - __uint_as_float((unsigned)hh1 << 16));
      }
      *(bf16x8*)&AsH[wb0] = h0; *(bf16x8*)&AsH[wb1] = h1;
      *(bf16x8*)&AsL[wb0] = l0; *(bf16x8*)&AsL[wb1] = l1;
      // ---- stage B: flat 16KB superblock copy ----
      {
        const int4* src = (const int4*)(Bhat + ((size_t)((t * 16 + nT) * 16) + (kc >> 5)) * 8192);
        int4* dst = (int4*)Bs;
#pragma unroll
        for (int q = 0; q < 4; ++q) dst[q * 256 + tid] = src[q * 256 + tid];
      }
      __syncthreads();
      // ---- MFMA: 64 per wave per chunk ----
      bf16x8 ah0 = *(const bf16x8*)&AsH[afo0];
      bf16x8 ah1 = *(const bf16x8*)&AsH[afo1];
      bf16x8 al0 = *(const bf16x8*)&AsL[afo0];
      bf16x8 al1 = *(const bf16x8*)&AsL[afo1];
#pragma unroll
      for (int g = 0; g < 8; ++g) {
#pragma unroll
        for (int ni = 0; ni < 2; ++ni) {
          bf16x8 bh = *(const bf16x8*)&Bs[(((g * 2 + ni) * 4 + quad) * 16 + l15) * 8];
          acc[g][0][ni] = __builtin_amdgcn_mfma_f32_16x16x32_bf16(ah0, bh, acc[g][0][ni], 0, 0, 0);
          acc[g][0][ni] = __builtin_amdgcn_mfma_f32_16x16x32_bf16(al0, bh, acc[g][0][ni], 0, 0, 0);
          acc[g][1][ni] = __builtin_amdgcn_mfma_f32_16x16x32_bf16(ah1, bh, acc[g][1][ni], 0, 0, 0);
          acc[g][1][ni] = __builtin_amdgcn_mfma_f32_16x16x32_bf16(al1, bh, acc[g][1][ni], 0, 0, 0);
        }
      }
    }
  }

  // ---- fused epilogue ----
  float biasr[8][2], dwdr[8][2], tdcv[2];
#pragma unroll
  for (int ni = 0; ni < 2; ++ni) {
    int col = n0 + ni * 16 + l15;
    tdcv[ni] = dc[bb * Hn + col];
#pragma unroll
    for (int g = 0; g < 8; ++g) {
      biasr[g][ni] = bias[g * Hn + col];
      dwdr[g][ni] = dWd[((size_t)g * Bn + bb) * Hn + col];
    }
  }

#pragma unroll
  for (int mi = 0; mi < 2; ++mi) {
#pragma unroll
    for (int r = 0; r < 4; ++r) {
      const int row = m0 + wid * 32 + mi * 16 + quad * 4 + r;
      const int srow = row & (Sn - 1);
      const float mf = (float)mask[row];
      const int pp = pos[row];
      const size_t rb = (size_t)row * Hn;
#pragma unroll
      for (int ni = 0; ni < 2; ++ni) {
        const int col = n0 + ni * 16 + l15;
        float cf = c[rb + col];
        float cb = 0.f, ca = 0.f;
        if (srow >= 1) cb = c[rb - Hn + col];
        if (srow >= 2) cb += c[rb - 2 * Hn + col];
        if (srow <= Sn - 2) ca = c[rb + Hn + col];
        if (srow <= Sn - 3) ca += c[rb + 2 * Hn + col];
        float sw = pp ? c[((size_t)(bb * Sn + pp - 1)) * Hn + col] : 0.f;
        float z[8];
#pragma unroll
        for (int g = 0; g < 8; ++g)
          z[g] = acc[g][mi][ni][r] + biasr[g][ni] + dwdr[g][ni];
        float e0 = __expf(sigf(z[0]));
        float e1 = __expf(sigf(z[1]));
        float e2 = __expf(sigf(z[2]));
        float e3 = __expf(sigf(z[3]));
        float e4 = __expf(sigf(z[4]));
        float e5 = __expf(sigf(z[5]));
        float inv = 1.f / (e0 + e1 + e2 + e3 + e4 + e5);
        float o = sigf(z[6]);
        float u = tanhf(z[7]);
        float cn = inv * (e0 * cb + e1 * ca + e2 * cf + e3 * tdcv[ni] + e4 * sw + e5 * u);
        cout[rb + col] = cn * mf;
        hout[rb + col] = o * tanhf(cn) * mf;
      }
    }
  }
}

extern "C" void kernel_launch(void* const* d_in, const int* in_sizes, int n_in,
                              void* d_out, int out_size, void* d_ws, size_t ws_size,
                              hipStream_t stream) {
  (void)in_sizes; (void)n_in; (void)out_size; (void)ws_size;
  const float* word   = (const float*)d_in[0];
  const float* init_h = (const float*)d_in[1];
  const float* init_c = (const float*)d_in[2];
  const float* Wx     = (const float*)d_in[3];
  const float* Wh     = (const float*)d_in[4];
  const float* Wi     = (const float*)d_in[5];
  const float* Wdm    = (const float*)d_in[6];
  const float* Wsm    = (const float*)d_in[7];
  const float* bias   = (const float*)d_in[8];
  const float* gW     = (const float*)d_in[9];
  const float* gb     = (const float*)d_in[10];
  const int*   pos    = (const int*)d_in[11];
  const int*   mask   = (const int*)d_in[12];

  float* ws = (float*)d_ws;
  size_t off = 0;
  auto alloc = [&](size_t nel) { float* p = ws + off; off += nel; return p; };
  float* hA   = alloc(NHe);
  float* hB   = alloc(NHe);
  float* cA   = alloc(NHe);
  float* cB   = alloc(NHe);
  float* G    = alloc(NHe);
  short* Bhat = (short*)alloc(5 * 8 * 512 * 512 / 2);  // 10.5M bf16 = 21MB
  float* dh   = alloc(Bn * Hn);
  float* dc   = alloc(Bn * Hn);
  float* dh2  = alloc(Bn * Hn);
  float* dc2  = alloc(Bn * Hn);
  float* comb = alloc(Bn * Hn);
  float* gd   = alloc(Bn * Hn);
  float* go   = alloc(Bn * Hn);
  float* gfA  = alloc(Bn * Hn);
  float* dWd  = alloc(8 * Bn * Hn);
  // total ~ 182 MB

  dim3 blk(256);
  int g4 = (int)(NHe / 4 / 256);          // 8192 blocks
  int gbh = (Bn * Hn) / 256;              // 64 blocks

  k_convw<<<dim3(16, 16, 40), dim3(64), 0, stream>>>(Wx, Wh, Wsm, Wi, Bhat);
  k_init<<<g4, blk, 0, stream>>>(init_h, init_c, mask, hA, cA);
  k_mean2<<<gbh, blk, 0, stream>>>(hA, cA, dh, dc);

  float* hcur = hA; float* hnxt = hB; float* ccur = cA; float* cnxt = cB;
  for (int l = 0; l < NLAYER; ++l) {
    k_mean1<<<gbh, blk, 0, stream>>>(hcur, comb);
    k_gates_small<<<gbh, blk, 0, stream>>>(dh, comb, gW, gb, gd, go, gfA);
    k_dWd<<<(8 * Bn * Hn) / 256, blk, 0, stream>>>(dh, Wdm, dWd);
    k_gemm1<<<dim3(Rn / 128, Hn / 128), blk, 0, stream>>>(hcur, gW + (size_t)5 * Hn * Hn, G);
    k_dummy<<<gbh, blk, 0, stream>>>(G, gfA, gd, go, ccur, dc, mask, dh2, dc2);

    float* hout = (l == NLAYER - 1) ? (float*)d_out : hnxt;
    k_mega<<<dim3(2048), blk, 0, stream>>>(
        hcur, ccur, word, Bhat, pos, mask, dc, dWd, bias, hout, cnxt);

    float* t1;
    t1 = hcur; hcur = hnxt; hnxt = t1;
    t1 = ccur; ccur = cnxt; cnxt = t1;
    t1 = dh; dh = dh2; dh2 = t1;
    t1 = dc; dc = dc2; dc2 = t1;
  }
}